// Round 7
// baseline (169.912 us; speedup 1.0000x reference)
//
#include <hip/hip_runtime.h>

typedef unsigned short u16;
typedef unsigned int u32;
typedef __attribute__((ext_vector_type(8))) __bf16 bf16x8;
typedef __attribute__((ext_vector_type(4))) float f32x4;

// ---- workspace layout (float offsets) ----
constexpr size_t OFF_PI  = 0;                    // pi fp32 [m][64]
constexpr size_t OFF_PBH = 512;                  // P hi bf16 [e][m][c][d] (u16)
constexpr size_t OFF_PBL = OFF_PBH + 1015808;    // P lo

union FR { uint4 u; bf16x8 v; };

// split x -> hi (RNE bf16) + lo (trunc bf16 of residual)
__device__ __forceinline__ void split_bf16(float x, u16& h, u16& l) {
  u32 b = __float_as_uint(x);
  u32 hb = (b + 0x7fffu + ((b >> 16) & 1u)) & 0xffff0000u;
  h = (u16)(hb >> 16);
  float r = x - __uint_as_float(hb);
  l = (u16)(__float_as_uint(r) >> 16);
}

__device__ __forceinline__ void split8(const f32x4 a, const f32x4 b,
                                       uint4& hi, uint4& lo) {
  u16 h[8], l[8];
  split_bf16(a.x, h[0], l[0]); split_bf16(a.y, h[1], l[1]);
  split_bf16(a.z, h[2], l[2]); split_bf16(a.w, h[3], l[3]);
  split_bf16(b.x, h[4], l[4]); split_bf16(b.y, h[5], l[5]);
  split_bf16(b.z, h[6], l[6]); split_bf16(b.w, h[7], l[7]);
  hi.x = h[0] | ((u32)h[1] << 16); hi.y = h[2] | ((u32)h[3] << 16);
  hi.z = h[4] | ((u32)h[5] << 16); hi.w = h[6] | ((u32)h[7] << 16);
  lo.x = l[0] | ((u32)l[1] << 16); lo.y = l[2] | ((u32)l[3] << 16);
  lo.z = l[4] | ((u32)l[5] << 16); lo.w = l[6] | ((u32)l[7] << 16);
}

__device__ __forceinline__ void mfma3(f32x4& a, const uint4 ah, const uint4 al,
                                      const uint4 bh, const uint4 bl) {
  FR Ah, Al, Bh, Bl;
  Ah.u = ah; Al.u = al; Bh.u = bh; Bl.u = bl;
  a = __builtin_amdgcn_mfma_f32_16x16x32_bf16(Ah.v, Bh.v, a, 0, 0, 0);
  a = __builtin_amdgcn_mfma_f32_16x16x32_bf16(Ah.v, Bl.v, a, 0, 0, 0);
  a = __builtin_amdgcn_mfma_f32_16x16x32_bf16(Al.v, Bh.v, a, 0, 0, 0);
}

// bf16 hi/lo matrix buffer (k_pcomb): 64 rows x 32 dwords hi + 2048 lo; 16B
// chunk j of row r at ((j+r)&7).
__device__ __forceinline__ void xt_read2(const u32* b, int row, int chunk,
                                         uint4& hi, uint4& lo) {
  const int dw = (row << 5) + (((chunk + row) & 7) << 2);
  hi = *(const uint4*)&b[dw];
  lo = *(const uint4*)&b[2048 + dw];
}
__device__ __forceinline__ void xt_write4(u32* b, int row, int cp, int half,
                                          const f32x4 v) {
  u16 h[4], l[4];
  split_bf16(v.x, h[0], l[0]); split_bf16(v.y, h[1], l[1]);
  split_bf16(v.z, h[2], l[2]); split_bf16(v.w, h[3], l[3]);
  const int dw = (row << 5) + (((cp + row) & 7) << 2) + half * 2;
  uint2 hh, ll;
  hh.x = h[0] | ((u32)h[1] << 16); hh.y = h[2] | ((u32)h[3] << 16);
  ll.x = l[0] | ((u32)l[1] << 16); ll.y = l[2] | ((u32)l[3] << 16);
  *(uint2*)&b[dw] = hh;
  *(uint2*)&b[2048 + dw] = ll;
}

// ---------------- K1: pi, Q, squaring ladder, Taylor combine -> P hi/lo -----
// 256 blocks: m = blk&7 (XCD-affine), part = blk>>3 covers 2 edges. Ladder is
// redundantly recomputed per block (cheap); 7 live matrix buffers (liveness
// reuse: R0 = rowQ1 then rowQ8) -> 132 KB LDS, 1 block/CU, all 256 CUs busy.
__global__ __launch_bounds__(1024) void k_pcomb(
    const float* __restrict__ R_inv, const float* __restrict__ pi_inv,
    const float* __restrict__ lengths, float* __restrict__ ws,
    u16* __restrict__ PBH, u16* __restrict__ PBL) {
  const int m = blockIdx.x & 7, prt = blockIdx.x >> 3;
  const int tid = threadIdx.x, lane = tid & 63, w = tid >> 6;
  const int ln = lane & 15, kq = lane >> 4;
  __shared__ float pis[64];
  __shared__ float n2s;
  __shared__ __align__(16) float Qs[64 * 68];  // reused as fp32 staging
  __shared__ __align__(16) u32 PB[7][4096];    // R0,R1,R2, C1..C4

  if (tid < 64) {
    float p = (tid < 63) ? pi_inv[m * 63 + tid] : 0.f;
    float v = p * p;
    #pragma unroll
    for (int off = 32; off; off >>= 1) v += __shfl_down(v, off, 64);
    if (tid == 0) n2s = v;
  }
  __syncthreads();
  if (tid < 64) {
    const float den = n2s + 1.f;
    const float x = (tid < 63) ? 2.f * pi_inv[m * 63 + tid] / den
                               : (n2s - 1.f) / den;
    const float pv = x * x;
    pis[tid] = pv;
    if (prt == 0) ws[OFF_PI + (size_t)m * 64 + tid] = pv;
  }
  __syncthreads();
  for (int idx = tid; idx < 4096; idx += 1024) {
    const int i = idx >> 6, j = idx & 63;
    float q = 0.f;
    if (i != j) {
      const int a = min(i, j), b = max(i, j);
      const int kk = a * (127 - a) / 2 + (b - a - 1);
      q = expf(R_inv[m * 2016 + kk]) * pis[j];
    }
    Qs[i * 68 + j] = q;
  }
  __syncthreads();
  if (tid < 64) {
    float s = 0.f;
    #pragma unroll 4
    for (int j4 = 0; j4 < 64; j4 += 4) {
      const f32x4 q = *(const f32x4*)&Qs[tid * 68 + j4];
      s += q.x + q.y + q.z + q.w;
    }
    Qs[tid * 68 + tid] = -s;
  }
  __syncthreads();
  // canonical Q1 (4 elems/thread) + row/col Q1 LDS layouts
  float q[12][4];
  const int ci0 = tid >> 4, cj0 = (tid & 15) * 4;
  #pragma unroll
  for (int r = 0; r < 4; ++r) q[0][r] = Qs[ci0 * 68 + cj0 + r];
  if (tid < 512) {
    const int i = tid >> 3, c = tid & 7;
    const f32x4 a = *(const f32x4*)&Qs[i * 68 + c * 8];
    const f32x4 b = *(const f32x4*)&Qs[i * 68 + c * 8 + 4];
    uint4 h, l;
    split8(a, b, h, l);
    const int dw = (i << 5) + (((c + i) & 7) << 2);
    *(uint4*)&PB[0][dw] = h;
    *(uint4*)&PB[0][2048 + dw] = l;
  } else {
    const int t2 = tid - 512, j = t2 >> 3, c = t2 & 7;
    f32x4 a, b;
    a.x = Qs[(c * 8 + 0) * 68 + j]; a.y = Qs[(c * 8 + 1) * 68 + j];
    a.z = Qs[(c * 8 + 2) * 68 + j]; a.w = Qs[(c * 8 + 3) * 68 + j];
    b.x = Qs[(c * 8 + 4) * 68 + j]; b.y = Qs[(c * 8 + 5) * 68 + j];
    b.z = Qs[(c * 8 + 6) * 68 + j]; b.w = Qs[(c * 8 + 7) * 68 + j];
    uint4 h, l;
    split8(a, b, h, l);
    const int dw = (j << 5) + (((c + j) & 7) << 2);
    *(uint4*)&PB[3][dw] = h;
    *(uint4*)&PB[3][2048 + dw] = l;
  }
  __syncthreads();

  const f32x4 z = {0.f, 0.f, 0.f, 0.f};
  const int ct = w >> 2, bt = w & 3;  // one 16x16 tile per wave
  auto mm = [&](const u32* RX, const u32* CY, u32* dstC, u32* dstR) {
    uint4 ah[2], al[2], bh[2], bl[2];
    #pragma unroll
    for (int kh = 0; kh < 2; ++kh) {
      xt_read2(RX, ct * 16 + ln, kh * 4 + kq, ah[kh], al[kh]);
      xt_read2(CY, bt * 16 + ln, kh * 4 + kq, bh[kh], bl[kh]);
    }
    f32x4 a = z;
    #pragma unroll
    for (int kh = 0; kh < 2; ++kh) mfma3(a, ah[kh], al[kh], bh[kh], bl[kh]);
    #pragma unroll
    for (int r = 0; r < 4; ++r)
      Qs[(ct * 16 + kq * 4 + r) * 64 + bt * 16 + ln] = a[r];
    if (dstC) xt_write4(dstC, bt * 16 + ln, 2 * ct + (kq >> 1), kq & 1, a);
    if (dstR) {
      #pragma unroll
      for (int kh = 0; kh < 2; ++kh) {
        xt_read2(CY, ct * 16 + ln, kh * 4 + kq, ah[kh], al[kh]);
        xt_read2(RX, bt * 16 + ln, kh * 4 + kq, bh[kh], bl[kh]);
      }
      f32x4 a2 = z;
      #pragma unroll
      for (int kh = 0; kh < 2; ++kh) mfma3(a2, ah[kh], al[kh], bh[kh], bl[kh]);
      xt_write4(dstR, bt * 16 + ln, 2 * ct + (kq >> 1), kq & 1, a2);
    }
  };
  auto step = [&](const u32* RX, const u32* CY, int k, u32* dstC, u32* dstR) {
    mm(RX, CY, dstC, dstR);
    __syncthreads();
    #pragma unroll
    for (int r = 0; r < 4; ++r) q[k - 1][r] = Qs[tid * 4 + r];
    __syncthreads();
  };
  // R0=rowQ1(->rowQ8), R1=rowQ2, R2=rowQ4, C1..C4 = colQ1..colQ4
  step(PB[0], PB[3], 2, PB[4], PB[1]);     // Q2 -> colQ2, rowQ2
  step(PB[1], PB[3], 3, PB[5], nullptr);   // Q3 -> colQ3
  step(PB[1], PB[4], 4, PB[6], PB[2]);     // Q4 -> colQ4, rowQ4
  step(PB[2], PB[3], 5, nullptr, nullptr);
  step(PB[2], PB[4], 6, nullptr, nullptr);
  step(PB[2], PB[5], 7, nullptr, nullptr);
  step(PB[2], PB[6], 8, nullptr, PB[0]);   // Q8 -> rowQ8 (R0 dead since Q2)
  step(PB[0], PB[3], 9, nullptr, nullptr);
  step(PB[0], PB[4], 10, nullptr, nullptr);
  step(PB[0], PB[5], 11, nullptr, nullptr);
  step(PB[0], PB[6], 12, nullptr, nullptr);

  // combine: 2 edges per block, all in registers
  #pragma unroll
  for (int ei = 0; ei < 2; ++ei) {
    const int e = prt * 2 + ei;
    if (e >= 62) break;
    const float t = lengths[e];
    float av[4] = {0.f, 0.f, 0.f, 0.f};
    const int dr = ci0 - cj0;
    if (dr >= 0 && dr < 4) av[dr] = 1.f;
    float cf = 1.f;
    #pragma unroll
    for (int k = 1; k <= 12; ++k) {
      cf *= t / (float)k;
      #pragma unroll
      for (int r = 0; r < 4; ++r) av[r] = fmaf(cf, q[k - 1][r], av[r]);
    }
    u16 h[4], l[4];
    split_bf16(av[0], h[0], l[0]); split_bf16(av[1], h[1], l[1]);
    split_bf16(av[2], h[2], l[2]); split_bf16(av[3], h[3], l[3]);
    const size_t base = (((size_t)e * 8 + m) << 12) + tid * 4;
    ushort4 h4, l4;
    h4.x = h[0]; h4.y = h[1]; h4.z = h[2]; h4.w = h[3];
    l4.x = l[0]; l4.y = l[1]; l4.z = l[2]; l4.w = l[3];
    *(ushort4*)(PBH + base) = h4;
    *(ushort4*)(PBL + base) = l4;
  }
}

// ---------------- K2: fused tree, 10-slot sliding-window schedule ----------
// 256 blocks = (m = blk&7 [XCD], btile of 32 cols) x 8 waves.
// 10 node slots x 8 KB = 80 KB -> 2 blocks/CU -> 4 waves/SIMD (the fix for
// the 2-waves/SIMD latency convoy of R4-R6). 31 pairs in 11 barrier-separated
// phases; every wave slices every pair as (ct=w>>1, bt=w&1).
// Schedule verified: a slot is only written when its previous value is dead,
// and root inputs S0/S4 are never clobbered.
#define SE(e, i0, i1, o) \
  ((u32)(e) | ((u32)(i0) << 8) | ((u32)(i1) << 16) | ((u32)(o) << 24))
__device__ const u32 SCHED[31] = {
    SE(0, 0, 0, 0),   SE(2, 0, 0, 1),   SE(4, 0, 0, 2),   SE(6, 0, 0, 3),
    SE(8, 0, 0, 4),   SE(10, 0, 0, 5),  SE(32, 0, 1, 6),  SE(34, 2, 3, 7),
    SE(12, 0, 0, 8),  SE(14, 0, 0, 9),  SE(36, 4, 5, 0),  SE(48, 6, 7, 1),
    SE(16, 0, 0, 2),  SE(18, 0, 0, 3),  SE(38, 8, 9, 4),  SE(20, 0, 0, 5),
    SE(50, 0, 4, 6),  SE(40, 2, 3, 7),  SE(22, 0, 0, 8),  SE(24, 0, 0, 9),
    SE(56, 1, 6, 0),  SE(42, 5, 8, 2),  SE(26, 0, 0, 3),  SE(28, 0, 0, 4),
    SE(52, 7, 2, 1),  SE(44, 9, 3, 5),  SE(30, 0, 0, 6),  SE(46, 4, 6, 2),
    SE(54, 5, 2, 3),  SE(58, 1, 3, 4),  SE(60, 0, 4, 15)};
__device__ const int PH[12] = {0, 4, 8, 12, 16, 20, 24, 27, 28, 29, 30, 31};

__global__ __launch_bounds__(512, 4) void k_tree(
    const float* __restrict__ leaves, const u16* __restrict__ Phi,
    const u16* __restrict__ Plo, const float* __restrict__ ws,
    float* __restrict__ out) {
  const int m = blockIdx.x & 7, btile = blockIdx.x >> 3;
  const int tid = threadIdx.x, lane = tid & 63, w = tid >> 6;
  const int ln = lane & 15, kq = lane >> 4;
  const int ct = w >> 1, bt = w & 1;
  const int row = bt * 16 + ln;  // batch row within the 32-col tile
  __shared__ __align__(16) u32 slots[10 * 2048];  // 80 KB
  __shared__ float psum[2][4][16];
  const f32x4 z = {0.f, 0.f, 0.f, 0.f};
  f32x4 rootpr = z;

  for (int phx = 0; phx < 11; ++phx) {
    const int pe = PH[phx + 1];
    for (int idx = PH[phx]; idx < pe; ++idx) {
      const u32 d = SCHED[idx];
      const int e0 = d & 0xff, i0 = (d >> 8) & 0xff, i1 = (d >> 16) & 0xff,
                os = d >> 24;
      // B fragments (both siblings)
      uint4 bh[2][2], bl[2][2];
      if (e0 < 32) {
        #pragma unroll
        for (int s = 0; s < 2; ++s)
          #pragma unroll
          for (int kh = 0; kh < 2; ++kh) {
            const float* g = leaves + (size_t)(btile * 32 + row) * 2048 +
                             (size_t)(e0 + s) * 64 + kh * 32 + kq * 8;
            const f32x4 xa = *(const f32x4*)g;
            const f32x4 xb = *(const f32x4*)(g + 4);
            split8(xa, xb, bh[s][kh], bl[s][kh]);
          }
      } else {
        #pragma unroll
        for (int s = 0; s < 2; ++s) {
          const u32* nb = &slots[(s ? i1 : i0) * 2048 + row * 64];
          #pragma unroll
          for (int kh = 0; kh < 2; ++kh) {
            const int jc = kh * 8 + kq * 2;
            const uint4 A = *(const uint4*)&nb[((jc + row) & 15) << 2];
            const uint4 B = *(const uint4*)&nb[((jc + 1 + row) & 15) << 2];
            bh[s][kh].x = A.x; bh[s][kh].y = A.y;
            bh[s][kh].z = B.x; bh[s][kh].w = B.y;
            bl[s][kh].x = A.z; bl[s][kh].y = A.w;
            bl[s][kh].z = B.z; bl[s][kh].w = B.w;
          }
        }
      }
      // P fragments (both siblings) for this wave's ct slice
      uint4 pfh[2][2], pfl[2][2];
      #pragma unroll
      for (int s = 0; s < 2; ++s) {
        const size_t pb = ((size_t)(e0 + s) * 8 + m) << 12;
        #pragma unroll
        for (int kh = 0; kh < 2; ++kh) {
          const size_t off = pb + (size_t)(ct * 16 + ln) * 64 + kh * 32 + kq * 8;
          pfh[s][kh] = *(const uint4*)(Phi + off);
          pfl[s][kh] = *(const uint4*)(Plo + off);
        }
      }
      // MFMA both siblings, product
      f32x4 a0 = z, a1 = z;
      #pragma unroll
      for (int kh = 0; kh < 2; ++kh) {
        mfma3(a0, pfh[0][kh], pfl[0][kh], bh[0][kh], bl[0][kh]);
        mfma3(a1, pfh[1][kh], pfl[1][kh], bh[1][kh], bl[1][kh]);
      }
      const f32x4 pr = a0 * a1;
      if (os == 15) {
        rootpr = pr;
      } else {
        // node write: interleaved h4|l4 16B chunk, XOR-swizzled
        u16 h[4], l[4];
        split_bf16(pr.x, h[0], l[0]); split_bf16(pr.y, h[1], l[1]);
        split_bf16(pr.z, h[2], l[2]); split_bf16(pr.w, h[3], l[3]);
        uint4 pk;
        pk.x = h[0] | ((u32)h[1] << 16); pk.y = h[2] | ((u32)h[3] << 16);
        pk.z = l[0] | ((u32)l[1] << 16); pk.w = l[2] | ((u32)l[3] << 16);
        const int jc = ct * 4 + kq;
        *(uint4*)&slots[os * 2048 + row * 64 + (((jc + row) & 15) << 2)] = pk;
      }
    }
    __syncthreads();
  }
  // root: dot with pi over states, reduce over kq, emit per batch col
  {
    const f32x4 piv =
        *(const f32x4*)&ws[OFF_PI + (size_t)m * 64 + ct * 16 + kq * 4];
    float v = rootpr.x * piv.x + rootpr.y * piv.y + rootpr.z * piv.z +
              rootpr.w * piv.w;
    v += __shfl_xor(v, 16, 64);
    v += __shfl_xor(v, 32, 64);
    if (lane < 16) psum[bt][ct][lane] = v;
  }
  __syncthreads();
  if (tid < 32) {
    const int bi = tid >> 4, bb = tid & 15;
    out[(size_t)(btile * 32 + tid) * 8 + m] =
        psum[bi][0][bb] + psum[bi][1][bb] + psum[bi][2][bb] + psum[bi][3][bb];
  }
}

extern "C" void kernel_launch(void* const* d_in, const int* in_sizes, int n_in,
                              void* d_out, int out_size, void* d_ws, size_t ws_size,
                              hipStream_t stream) {
  const float* leaves  = (const float*)d_in[0];  // (B, 32, 64)
  const float* R_inv   = (const float*)d_in[1];  // (8, 2016)
  const float* pi_inv  = (const float*)d_in[2];  // (8, 63)
  const float* lengths = (const float*)d_in[3];  // (62,)
  float* out = (float*)d_out;                    // (B, 8)
  float* ws  = (float*)d_ws;

  u16* PBH = (u16*)(ws + OFF_PBH);
  u16* PBL = (u16*)(ws + OFF_PBL);

  hipLaunchKernelGGL(k_pcomb, dim3(256), dim3(1024), 0, stream, R_inv, pi_inv,
                     lengths, ws, PBH, PBL);
  hipLaunchKernelGGL(k_tree, dim3(256), dim3(512), 0, stream, leaves, PBH, PBL,
                     ws, out);
}

// Round 8
// 127.636 us; speedup vs baseline: 1.3312x; 1.3312x over previous
//
#include <hip/hip_runtime.h>

typedef unsigned short u16;
typedef unsigned int u32;
typedef __attribute__((ext_vector_type(8))) __bf16 bf16x8;
typedef __attribute__((ext_vector_type(4))) float f32x4;

// ---- workspace layout (float offsets) ----
constexpr size_t OFF_PI  = 0;                    // pi fp32 [m][64]
constexpr size_t OFF_PBH = 512;                  // P hi bf16 [e][m][c][d] (u16)
constexpr size_t OFF_PBL = OFF_PBH + 1015808;    // P lo

union FR { uint4 u; bf16x8 v; };

// split x -> hi (RNE bf16) + lo (trunc bf16 of residual)
__device__ __forceinline__ void split_bf16(float x, u16& h, u16& l) {
  u32 b = __float_as_uint(x);
  u32 hb = (b + 0x7fffu + ((b >> 16) & 1u)) & 0xffff0000u;
  h = (u16)(hb >> 16);
  float r = x - __uint_as_float(hb);
  l = (u16)(__float_as_uint(r) >> 16);
}

__device__ __forceinline__ void split8(const f32x4 a, const f32x4 b,
                                       uint4& hi, uint4& lo) {
  u16 h[8], l[8];
  split_bf16(a.x, h[0], l[0]); split_bf16(a.y, h[1], l[1]);
  split_bf16(a.z, h[2], l[2]); split_bf16(a.w, h[3], l[3]);
  split_bf16(b.x, h[4], l[4]); split_bf16(b.y, h[5], l[5]);
  split_bf16(b.z, h[6], l[6]); split_bf16(b.w, h[7], l[7]);
  hi.x = h[0] | ((u32)h[1] << 16); hi.y = h[2] | ((u32)h[3] << 16);
  hi.z = h[4] | ((u32)h[5] << 16); hi.w = h[6] | ((u32)h[7] << 16);
  lo.x = l[0] | ((u32)l[1] << 16); lo.y = l[2] | ((u32)l[3] << 16);
  lo.z = l[4] | ((u32)l[5] << 16); lo.w = l[6] | ((u32)l[7] << 16);
}

__device__ __forceinline__ void mfma3(f32x4& a, const uint4 ah, const uint4 al,
                                      const uint4 bh, const uint4 bl) {
  FR Ah, Al, Bh, Bl;
  Ah.u = ah; Al.u = al; Bh.u = bh; Bl.u = bl;
  a = __builtin_amdgcn_mfma_f32_16x16x32_bf16(Ah.v, Bh.v, a, 0, 0, 0);
  a = __builtin_amdgcn_mfma_f32_16x16x32_bf16(Ah.v, Bl.v, a, 0, 0, 0);
  a = __builtin_amdgcn_mfma_f32_16x16x32_bf16(Al.v, Bh.v, a, 0, 0, 0);
}

// bf16 hi/lo matrix buffer (k_pcomb): 64 rows x 32 dwords hi + 2048 lo; 16B
// chunk j of row r at ((j+r)&7).
__device__ __forceinline__ void xt_read2(const u32* b, int row, int chunk,
                                         uint4& hi, uint4& lo) {
  const int dw = (row << 5) + (((chunk + row) & 7) << 2);
  hi = *(const uint4*)&b[dw];
  lo = *(const uint4*)&b[2048 + dw];
}
__device__ __forceinline__ void xt_write4(u32* b, int row, int cp, int half,
                                          const f32x4 v) {
  u16 h[4], l[4];
  split_bf16(v.x, h[0], l[0]); split_bf16(v.y, h[1], l[1]);
  split_bf16(v.z, h[2], l[2]); split_bf16(v.w, h[3], l[3]);
  const int dw = (row << 5) + (((cp + row) & 7) << 2) + half * 2;
  uint2 hh, ll;
  hh.x = h[0] | ((u32)h[1] << 16); hh.y = h[2] | ((u32)h[3] << 16);
  ll.x = l[0] | ((u32)l[1] << 16); ll.y = l[2] | ((u32)l[3] << 16);
  *(uint2*)&b[dw] = hh;
  *(uint2*)&b[2048 + dw] = ll;
}

// ---------------- K1: pi, Q, squaring ladder, Taylor combine -> P hi/lo -----
// 256 blocks: m = blk&7 (XCD-affine), prt = blk>>3 covers 2 edges. All 12
// power C-frags stay in registers (q[12][4], C-layout); only 5 barriers.
__global__ __launch_bounds__(1024) void k_pcomb(
    const float* __restrict__ R_inv, const float* __restrict__ pi_inv,
    const float* __restrict__ lengths, float* __restrict__ ws,
    u16* __restrict__ PBH, u16* __restrict__ PBL) {
  const int m = blockIdx.x & 7, prt = blockIdx.x >> 3;
  const int tid = threadIdx.x, lane = tid & 63, w = tid >> 6;
  const int ln = lane & 15, kq = lane >> 4;
  const int ct = w >> 2, bt = w & 3;  // one 16x16 tile per wave (16 waves)
  __shared__ float pis[64];
  __shared__ float n2s;
  __shared__ __align__(16) float Qs[64 * 68];
  __shared__ __align__(16) u32 PB[7][4096];  // R0(Q1->Q8),R1(Q2),R2(Q4),C1..C4

  if (tid < 64) {
    float p = (tid < 63) ? pi_inv[m * 63 + tid] : 0.f;
    float v = p * p;
    #pragma unroll
    for (int off = 32; off; off >>= 1) v += __shfl_down(v, off, 64);
    if (tid == 0) n2s = v;
  }
  __syncthreads();
  if (tid < 64) {
    const float den = n2s + 1.f;
    const float x = (tid < 63) ? 2.f * pi_inv[m * 63 + tid] / den
                               : (n2s - 1.f) / den;
    const float pv = x * x;
    pis[tid] = pv;
    if (prt == 0) ws[OFF_PI + (size_t)m * 64 + tid] = pv;
  }
  __syncthreads();
  for (int idx = tid; idx < 4096; idx += 1024) {
    const int i = idx >> 6, j = idx & 63;
    float q = 0.f;
    if (i != j) {
      const int a = min(i, j), b = max(i, j);
      const int kk = a * (127 - a) / 2 + (b - a - 1);
      q = expf(R_inv[m * 2016 + kk]) * pis[j];
    }
    Qs[i * 68 + j] = q;
  }
  __syncthreads();
  if (tid < 64) {
    float s = 0.f;
    #pragma unroll 4
    for (int j4 = 0; j4 < 64; j4 += 4) {
      const f32x4 q = *(const f32x4*)&Qs[tid * 68 + j4];
      s += q.x + q.y + q.z + q.w;
    }
    Qs[tid * 68 + tid] = -s;
  }
  __syncthreads();
  // q[k][r] = (Q^{k+1})[ct*16+kq*4+r][bt*16+ln]  (MFMA C-layout, registers)
  float q[12][4];
  #pragma unroll
  for (int r = 0; r < 4; ++r) q[0][r] = Qs[(ct * 16 + kq * 4 + r) * 68 + bt * 16 + ln];
  if (tid < 512) {  // row-layout Q1 -> PB[0]
    const int i = tid >> 3, c = tid & 7;
    const f32x4 a = *(const f32x4*)&Qs[i * 68 + c * 8];
    const f32x4 b = *(const f32x4*)&Qs[i * 68 + c * 8 + 4];
    uint4 h, l;
    split8(a, b, h, l);
    const int dw = (i << 5) + (((c + i) & 7) << 2);
    *(uint4*)&PB[0][dw] = h;
    *(uint4*)&PB[0][2048 + dw] = l;
  } else {  // col-layout Q1 -> PB[3]
    const int t2 = tid - 512, j = t2 >> 3, c = t2 & 7;
    f32x4 a, b;
    a.x = Qs[(c * 8 + 0) * 68 + j]; a.y = Qs[(c * 8 + 1) * 68 + j];
    a.z = Qs[(c * 8 + 2) * 68 + j]; a.w = Qs[(c * 8 + 3) * 68 + j];
    b.x = Qs[(c * 8 + 4) * 68 + j]; b.y = Qs[(c * 8 + 5) * 68 + j];
    b.z = Qs[(c * 8 + 6) * 68 + j]; b.w = Qs[(c * 8 + 7) * 68 + j];
    uint4 h, l;
    split8(a, b, h, l);
    const int dw = (j << 5) + (((c + j) & 7) << 2);
    *(uint4*)&PB[3][dw] = h;
    *(uint4*)&PB[3][2048 + dw] = l;
  }
  __syncthreads();

  const f32x4 z = {0.f, 0.f, 0.f, 0.f};
  auto mmstep = [&](const u32* RX, const u32* CY, float* qk, u32* dstC,
                    u32* dstR) {
    uint4 ah[2], al[2], bh[2], bl[2];
    #pragma unroll
    for (int kh = 0; kh < 2; ++kh) {
      xt_read2(RX, ct * 16 + ln, kh * 4 + kq, ah[kh], al[kh]);
      xt_read2(CY, bt * 16 + ln, kh * 4 + kq, bh[kh], bl[kh]);
    }
    f32x4 a = z;
    #pragma unroll
    for (int kh = 0; kh < 2; ++kh) mfma3(a, ah[kh], al[kh], bh[kh], bl[kh]);
    #pragma unroll
    for (int r = 0; r < 4; ++r) qk[r] = a[r];
    if (dstC) xt_write4(dstC, bt * 16 + ln, 2 * ct + (kq >> 1), kq & 1, a);
    if (dstR) {  // Z^T = Y^T * X^T
      #pragma unroll
      for (int kh = 0; kh < 2; ++kh) {
        xt_read2(CY, ct * 16 + ln, kh * 4 + kq, ah[kh], al[kh]);
        xt_read2(RX, bt * 16 + ln, kh * 4 + kq, bh[kh], bl[kh]);
      }
      f32x4 a2 = z;
      #pragma unroll
      for (int kh = 0; kh < 2; ++kh) mfma3(a2, ah[kh], al[kh], bh[kh], bl[kh]);
      xt_write4(dstR, bt * 16 + ln, 2 * ct + (kq >> 1), kq & 1, a2);
    }
  };
  mmstep(PB[0], PB[3], q[1], PB[4], PB[1]);  __syncthreads();  // Q2
  mmstep(PB[1], PB[3], q[2], PB[5], nullptr); __syncthreads(); // Q3
  mmstep(PB[1], PB[4], q[3], PB[6], PB[2]);  __syncthreads();  // Q4
  mmstep(PB[2], PB[3], q[4], nullptr, nullptr);                // Q5
  mmstep(PB[2], PB[4], q[5], nullptr, nullptr);                // Q6
  mmstep(PB[2], PB[5], q[6], nullptr, nullptr);                // Q7
  mmstep(PB[2], PB[6], q[7], nullptr, PB[0]); __syncthreads(); // Q8 -> rowQ8
  mmstep(PB[0], PB[3], q[8], nullptr, nullptr);                // Q9
  mmstep(PB[0], PB[4], q[9], nullptr, nullptr);                // Q10
  mmstep(PB[0], PB[5], q[10], nullptr, nullptr);               // Q11
  mmstep(PB[0], PB[6], q[11], nullptr, nullptr);               // Q12

  // combine: 2 edges per block, all in registers (C-layout scatter store)
  #pragma unroll
  for (int ei = 0; ei < 2; ++ei) {
    const int e = prt * 2 + ei;
    if (e >= 62) break;
    const float t = lengths[e];
    const int jcol = bt * 16 + ln;
    float av[4];
    #pragma unroll
    for (int r = 0; r < 4; ++r)
      av[r] = (ct * 16 + kq * 4 + r == jcol) ? 1.f : 0.f;
    float cf = 1.f;
    #pragma unroll
    for (int k = 1; k <= 12; ++k) {
      cf *= t / (float)k;
      #pragma unroll
      for (int r = 0; r < 4; ++r) av[r] = fmaf(cf, q[k - 1][r], av[r]);
    }
    const size_t base = (((size_t)e * 8 + m) << 12) + jcol;
    #pragma unroll
    for (int r = 0; r < 4; ++r) {
      u16 h, l;
      split_bf16(av[r], h, l);
      const size_t o = base + (size_t)(ct * 16 + kq * 4 + r) * 64;
      PBH[o] = h;
      PBL[o] = l;
    }
  }
}

// ---------------- K2: fused tree, 9-slot sliding window, ct-split ----------
// 256 blocks = (m = blk&7 [XCD], btile of 32 cols) x 8 waves.
// 9 slots x 8 KB = 72 KB (+psum) -> 2 blocks/CU -> 4 waves/SIMD.
// 31 pairs in 11 phases; 2 waves per pair (ct-halves), each wave does
// 2ct x 2bt = 48 MFMA per 16 P-uint4 loads (3:1, P not duplicated).
// Liveness of the 9-slot schedule hand-verified (see session notes).
#define SE(e, i0, i1, o) \
  ((u32)(e) | ((u32)(i0) << 8) | ((u32)(i1) << 16) | ((u32)(o) << 24))
__device__ const u32 SCHED[31] = {
    SE(0, 0, 0, 0),  SE(2, 0, 0, 1),  SE(4, 0, 0, 2),  SE(6, 0, 0, 3),
    SE(32, 0, 1, 4), SE(34, 2, 3, 5), SE(8, 0, 0, 6),  SE(10, 0, 0, 7),
    SE(36, 6, 7, 8), SE(12, 0, 0, 0), SE(14, 0, 0, 1), SE(16, 0, 0, 2),
    SE(38, 0, 1, 3), SE(48, 4, 5, 6), SE(18, 0, 0, 7),
    SE(40, 2, 7, 0), SE(50, 8, 3, 1), SE(20, 0, 0, 4), SE(22, 0, 0, 5),
    SE(42, 4, 5, 2), SE(24, 0, 0, 3), SE(26, 0, 0, 7), SE(56, 6, 1, 8),
    SE(52, 0, 2, 1), SE(44, 3, 7, 4), SE(28, 0, 0, 5), SE(30, 0, 0, 6),
    SE(46, 5, 6, 0),
    SE(54, 4, 0, 2),
    SE(58, 1, 2, 3),
    SE(60, 8, 3, 15)};
__device__ const int PH[12] = {0, 4, 8, 12, 15, 19, 23, 27, 28, 29, 30, 31};

__global__ __launch_bounds__(512, 4) void k_tree(
    const float* __restrict__ leaves, const u16* __restrict__ Phi,
    const u16* __restrict__ Plo, const float* __restrict__ ws,
    float* __restrict__ out) {
  const int m = blockIdx.x & 7, btile = blockIdx.x >> 3;
  const int tid = threadIdx.x, lane = tid & 63, w = tid >> 6;
  const int ln = lane & 15, kq = lane >> 4;
  const int ct0 = (w & 1) * 2;  // this wave's ct-half
  __shared__ __align__(16) u32 slots[9 * 2048];  // 72 KB
  __shared__ float psum[2][4][16];
  const f32x4 z = {0.f, 0.f, 0.f, 0.f};
  f32x4 rootp[2][2] = {{z, z}, {z, z}};

  for (int ph = 0; ph < 11; ++ph) {
    const int p0 = PH[ph], np = PH[ph + 1] - p0;
    const int pi = w >> 1;
    if (pi < np) {
      const u32 d = SCHED[p0 + pi];
      const int e0 = d & 0xff, i0 = (d >> 8) & 0xff, i1 = (d >> 16) & 0xff,
                os = d >> 24;
      f32x4 acc[2][2];  // [ci][bt]
      #pragma unroll
      for (int s = 0; s < 2; ++s) {
        // B fragments for this sibling (both bt rows)
        uint4 bh[2][2], bl[2][2];  // [bt][kh]
        if (e0 < 32) {
          #pragma unroll
          for (int bi = 0; bi < 2; ++bi) {
            const int row = bi * 16 + ln;
            #pragma unroll
            for (int kh = 0; kh < 2; ++kh) {
              const float* g = leaves + (size_t)(btile * 32 + row) * 2048 +
                               (size_t)(e0 + s) * 64 + kh * 32 + kq * 8;
              const f32x4 xa = *(const f32x4*)g;
              const f32x4 xb = *(const f32x4*)(g + 4);
              split8(xa, xb, bh[bi][kh], bl[bi][kh]);
            }
          }
        } else {
          const u32* nb0 = &slots[(s ? i1 : i0) * 2048];
          #pragma unroll
          for (int bi = 0; bi < 2; ++bi) {
            const int row = bi * 16 + ln;
            const u32* nb = nb0 + row * 64;
            #pragma unroll
            for (int kh = 0; kh < 2; ++kh) {
              const int jc = kh * 8 + kq * 2;
              const uint4 A = *(const uint4*)&nb[((jc + row) & 15) << 2];
              const uint4 B = *(const uint4*)&nb[((jc + 1 + row) & 15) << 2];
              bh[bi][kh].x = A.x; bh[bi][kh].y = A.y;
              bh[bi][kh].z = B.x; bh[bi][kh].w = B.y;
              bl[bi][kh].x = A.z; bl[bi][kh].y = A.w;
              bl[bi][kh].z = B.z; bl[bi][kh].w = B.w;
            }
          }
        }
        // P fragments: 2 ct tiles for this sibling
        uint4 pfh[2][2], pfl[2][2];  // [ci][kh]
        const size_t pb = ((size_t)(e0 + s) * 8 + m) << 12;
        #pragma unroll
        for (int ci = 0; ci < 2; ++ci)
          #pragma unroll
          for (int kh = 0; kh < 2; ++kh) {
            const size_t off =
                pb + (size_t)((ct0 + ci) * 16 + ln) * 64 + kh * 32 + kq * 8;
            pfh[ci][kh] = *(const uint4*)(Phi + off);
            pfl[ci][kh] = *(const uint4*)(Plo + off);
          }
        // MFMA
        #pragma unroll
        for (int ci = 0; ci < 2; ++ci)
          #pragma unroll
          for (int bi = 0; bi < 2; ++bi) {
            f32x4 a = z;
            #pragma unroll
            for (int kh = 0; kh < 2; ++kh)
              mfma3(a, pfh[ci][kh], pfl[ci][kh], bh[bi][kh], bl[bi][kh]);
            if (s == 0) {
              acc[ci][bi] = a;
            } else {
              const f32x4 pr = acc[ci][bi] * a;
              if (os == 15) {
                rootp[ci][bi] = pr;
              } else {
                u16 h[4], l[4];
                split_bf16(pr.x, h[0], l[0]); split_bf16(pr.y, h[1], l[1]);
                split_bf16(pr.z, h[2], l[2]); split_bf16(pr.w, h[3], l[3]);
                uint4 pk;
                pk.x = h[0] | ((u32)h[1] << 16); pk.y = h[2] | ((u32)h[3] << 16);
                pk.z = l[0] | ((u32)l[1] << 16); pk.w = l[2] | ((u32)l[3] << 16);
                const int row = bi * 16 + ln;
                const int jc = (ct0 + ci) * 4 + kq;
                *(uint4*)&slots[os * 2048 + row * 64 +
                                (((jc + row) & 15) << 2)] = pk;
              }
            }
          }
      }
    }
    __syncthreads();
  }
  // root: dot with pi, reduce over kq, emit per batch col
  if (w < 2) {
    #pragma unroll
    for (int ci = 0; ci < 2; ++ci) {
      const int ct = ct0 + ci;
      const f32x4 piv =
          *(const f32x4*)&ws[OFF_PI + (size_t)m * 64 + ct * 16 + kq * 4];
      #pragma unroll
      for (int bi = 0; bi < 2; ++bi) {
        const f32x4 pr = rootp[ci][bi];
        float v = pr.x * piv.x + pr.y * piv.y + pr.z * piv.z + pr.w * piv.w;
        v += __shfl_xor(v, 16, 64);
        v += __shfl_xor(v, 32, 64);
        if (lane < 16) psum[bi][ct][lane] = v;
      }
    }
  }
  __syncthreads();
  if (tid < 32) {
    const int bi = tid >> 4, bb = tid & 15;
    out[(size_t)(btile * 32 + tid) * 8 + m] =
        psum[bi][0][bb] + psum[bi][1][bb] + psum[bi][2][bb] + psum[bi][3][bb];
  }
}

extern "C" void kernel_launch(void* const* d_in, const int* in_sizes, int n_in,
                              void* d_out, int out_size, void* d_ws, size_t ws_size,
                              hipStream_t stream) {
  const float* leaves  = (const float*)d_in[0];  // (B, 32, 64)
  const float* R_inv   = (const float*)d_in[1];  // (8, 2016)
  const float* pi_inv  = (const float*)d_in[2];  // (8, 63)
  const float* lengths = (const float*)d_in[3];  // (62,)
  float* out = (float*)d_out;                    // (B, 8)
  float* ws  = (float*)d_ws;

  u16* PBH = (u16*)(ws + OFF_PBH);
  u16* PBL = (u16*)(ws + OFF_PBL);

  hipLaunchKernelGGL(k_pcomb, dim3(256), dim3(1024), 0, stream, R_inv, pi_inv,
                     lengths, ws, PBH, PBL);
  hipLaunchKernelGGL(k_tree, dim3(256), dim3(512), 0, stream, leaves, PBH, PBL,
                     ws, out);
}